// Round 1
// baseline (895.909 us; speedup 1.0000x reference)
//
#include <hip/hip_runtime.h>
#include <math.h>

#define B_ 128
#define S_ 2048
#define H_ 512
#define V_ 32000
#define NCH 8          // s-chunks per batch for attention
#define NW 4           // waves per block
#define NP (NCH * NW)  // partials per batch = 32

typedef __attribute__((ext_vector_type(8))) short bf16x8;
typedef __attribute__((ext_vector_type(4))) float f32x4;

// fp32 -> bf16 round-to-nearest-even (bit trick), and back.
__device__ __forceinline__ short f2bf(float f) {
  union { float f; unsigned u; } v;
  v.f = f;
  unsigned r = v.u + 0x7fffu + ((v.u >> 16) & 1u);
  return (short)(r >> 16);
}
__device__ __forceinline__ float bf2f(short s) {
  union { unsigned u; float f; } v;
  v.u = ((unsigned)(unsigned short)s) << 16;
  return v.f;
}

// ---------------------------------------------------------------------------
// Generic tiled fp32 GEMM body: C[M,N] = A[M,K] @ B[N,K]^T + bias[N], opt tanh.
// A rows optionally gathered via arows (embedding lookup).
// threads = (BM/TM)*(BN/TN) must equal 256.
// ---------------------------------------------------------------------------
template <int BM, int BN, int BK, int TM, int TN, int ACT>
__device__ __forceinline__ void gemm_body(
    const float* __restrict__ A, const int* __restrict__ arows,
    const float* __restrict__ Bm, const float* __restrict__ bias,
    float* __restrict__ C, int M, int N, int K, int bx, int by) {
  __shared__ float As[BK][BM + 4];
  __shared__ float Bs[BK][BN + 4];
  const int tid = threadIdx.x;
  const int tx = tid % (BN / TN);
  const int ty = tid / (BN / TN);
  const int n0 = bx * BN;
  const int m0 = by * BM;

  float acc[TM][TN];
#pragma unroll
  for (int i = 0; i < TM; i++)
#pragma unroll
    for (int j = 0; j < TN; j++) acc[i][j] = 0.f;

  for (int k0 = 0; k0 < K; k0 += BK) {
#pragma unroll
    for (int e = tid; e < BM * BK; e += 256) {
      int m = e / BK, kk = e % BK;
      int row = arows ? arows[m0 + m] : (m0 + m);
      As[kk][m] = A[(long)row * K + k0 + kk];
    }
#pragma unroll
    for (int e = tid; e < BN * BK; e += 256) {
      int n = e / BK, kk = e % BK;
      Bs[kk][n] = Bm[(long)(n0 + n) * K + k0 + kk];
    }
    __syncthreads();
#pragma unroll
    for (int kk = 0; kk < BK; kk++) {
      float av[TM], bv[TN];
#pragma unroll
      for (int i = 0; i < TM; i++) av[i] = As[kk][ty * TM + i];
#pragma unroll
      for (int j = 0; j < TN; j++) bv[j] = Bs[kk][tx * TN + j];
#pragma unroll
      for (int i = 0; i < TM; i++)
#pragma unroll
        for (int j = 0; j < TN; j++) acc[i][j] = fmaf(av[i], bv[j], acc[i][j]);
    }
    __syncthreads();
  }

#pragma unroll
  for (int i = 0; i < TM; i++) {
    int m = m0 + ty * TM + i;
#pragma unroll
    for (int j = 0; j < TN; j++) {
      int n = n0 + tx * TN + j;
      float c = acc[i][j] + bias[n];
      if (ACT == 1) c = tanhf(c);
      C[(long)m * N + n] = c;
    }
  }
}

template <int BM, int BN, int BK, int TM, int TN, int ACT>
__global__ __launch_bounds__(256) void gemm_tn(
    const float* __restrict__ A, const int* __restrict__ arows,
    const float* __restrict__ Bm, const float* __restrict__ bias,
    float* __restrict__ C, int M, int N, int K) {
  gemm_body<BM, BN, BK, TM, TN, ACT>(A, arows, Bm, bias, C, M, N, K,
                                     blockIdx.x, blockIdx.y);
}

// ---------------------------------------------------------------------------
// Both GRU gate GEMMs in ONE launch (blockIdx.z selects gi vs gh) so the two
// 192-block GEMMs overlap (384 blocks -> 1.5 blocks/CU instead of 2x 0.75).
// ---------------------------------------------------------------------------
__global__ __launch_bounds__(256) void gru_gates(
    const float* __restrict__ emb, const int* __restrict__ idx,
    const float* __restrict__ hlast, const float* __restrict__ w_ih,
    const float* __restrict__ w_hh, const float* __restrict__ b_ih,
    const float* __restrict__ b_hh, float* __restrict__ gi,
    float* __restrict__ gh) {
  if (blockIdx.z == 0)
    gemm_body<32, 32, 16, 2, 2, 0>(emb, idx, w_ih, b_ih, gi, B_, 3 * H_, H_,
                                   blockIdx.x, blockIdx.y);
  else
    gemm_body<32, 32, 16, 2, 2, 0>(hlast, nullptr, w_hh, b_hh, gh, B_, 3 * H_,
                                   H_, blockIdx.x, blockIdx.y);
}

// ---------------------------------------------------------------------------
// Output GEMM via MFMA, bf16 hi/lo split (3 MFMA passes ~= fp32 accuracy):
//   C[M,N] = A[M,K] @ B[N,K]^T + bias[N], fp32 in/out.
// Block: 256 thr = 4 waves; tile 64(M) x 128(N), BK=64; wave tile 64x32
// (M_rep=4, N_rep=2 of 16x16x32). fp32 -> bf16 hi/lo conversion happens
// inline during LDS staging (reads global fp32 exactly once).
// LDS rows padded to 72 bf16 (144 B) -> frag ds_read_b128 is ~2-way max.
// ---------------------------------------------------------------------------
__global__ __launch_bounds__(256) void gemm_mfma_split(
    const float* __restrict__ A, const float* __restrict__ Bm,
    const float* __restrict__ bias, float* __restrict__ C, int M, int N,
    int K) {
  __shared__ __align__(16) short Ah[64][72];
  __shared__ __align__(16) short Al[64][72];
  __shared__ __align__(16) short Bh[128][72];
  __shared__ __align__(16) short Bl[128][72];

  const int tid = threadIdx.x;
  const int wv = tid >> 6;
  const int lane = tid & 63;
  const int m0 = blockIdx.y * 64;
  const int n0 = blockIdx.x * 128;

  f32x4 acc[4][2];
#pragma unroll
  for (int i = 0; i < 4; i++)
#pragma unroll
    for (int j = 0; j < 2; j++) acc[i][j] = (f32x4){0.f, 0.f, 0.f, 0.f};

  // staging coordinates
  const int ar = tid >> 2;          // A row 0..63 (4 thr/row)
  const int ac = (tid & 3) << 4;    // A col chunk: 16 floats
  const int br = tid >> 1;          // B row 0..127 (2 thr/row)
  const int bc = (tid & 1) << 5;    // B col chunk: 32 floats

  const int rr = lane & 15;
  const int kg = (lane >> 4) << 3;  // k-slot base within 32-wide k-step

  for (int k0 = 0; k0 < K; k0 += 64) {
    // ---- stage A tile (64x64 fp32 -> bf16 hi/lo) ----
    {
      const float4* src = (const float4*)(A + (long)(m0 + ar) * K + k0 + ac);
      float4 fv[4];
#pragma unroll
      for (int q = 0; q < 4; q++) fv[q] = src[q];
#pragma unroll
      for (int q = 0; q < 2; q++) {
        float4 u = fv[2 * q], w = fv[2 * q + 1];
        float x[8] = {u.x, u.y, u.z, u.w, w.x, w.y, w.z, w.w};
        bf16x8 hh, ll;
#pragma unroll
        for (int j = 0; j < 8; j++) {
          short h = f2bf(x[j]);
          hh[j] = h;
          ll[j] = f2bf(x[j] - bf2f(h));
        }
        *(bf16x8*)&Ah[ar][ac + q * 8] = hh;
        *(bf16x8*)&Al[ar][ac + q * 8] = ll;
      }
    }
    // ---- stage B tile (128x64 fp32 -> bf16 hi/lo) ----
    {
      const float4* src = (const float4*)(Bm + (long)(n0 + br) * K + k0 + bc);
      float4 fv[8];
#pragma unroll
      for (int q = 0; q < 8; q++) fv[q] = src[q];
#pragma unroll
      for (int q = 0; q < 4; q++) {
        float4 u = fv[2 * q], w = fv[2 * q + 1];
        float x[8] = {u.x, u.y, u.z, u.w, w.x, w.y, w.z, w.w};
        bf16x8 hh, ll;
#pragma unroll
        for (int j = 0; j < 8; j++) {
          short h = f2bf(x[j]);
          hh[j] = h;
          ll[j] = f2bf(x[j] - bf2f(h));
        }
        *(bf16x8*)&Bh[br][bc + q * 8] = hh;
        *(bf16x8*)&Bl[br][bc + q * 8] = ll;
      }
    }
    __syncthreads();

#pragma unroll
    for (int ks = 0; ks < 2; ks++) {
      const int kb = ks * 32 + kg;
      bf16x8 a_h[4], a_l[4], b_h[2], b_l[2];
#pragma unroll
      for (int i = 0; i < 4; i++) {
        a_h[i] = *(const bf16x8*)&Ah[i * 16 + rr][kb];
        a_l[i] = *(const bf16x8*)&Al[i * 16 + rr][kb];
      }
#pragma unroll
      for (int j = 0; j < 2; j++) {
        b_h[j] = *(const bf16x8*)&Bh[wv * 32 + j * 16 + rr][kb];
        b_l[j] = *(const bf16x8*)&Bl[wv * 32 + j * 16 + rr][kb];
      }
#pragma unroll
      for (int i = 0; i < 4; i++)
#pragma unroll
        for (int j = 0; j < 2; j++) {
          acc[i][j] = __builtin_amdgcn_mfma_f32_16x16x32_bf16(
              a_h[i], b_h[j], acc[i][j], 0, 0, 0);
          acc[i][j] = __builtin_amdgcn_mfma_f32_16x16x32_bf16(
              a_h[i], b_l[j], acc[i][j], 0, 0, 0);
          acc[i][j] = __builtin_amdgcn_mfma_f32_16x16x32_bf16(
              a_l[i], b_h[j], acc[i][j], 0, 0, 0);
        }
    }
    __syncthreads();
  }

  // epilogue: C/D layout col=lane&15, row=(lane>>4)*4+reg  [m89-verified]
  const int rg = lane >> 4;
#pragma unroll
  for (int i = 0; i < 4; i++) {
#pragma unroll
    for (int j = 0; j < 2; j++) {
      int col = n0 + wv * 32 + j * 16 + rr;
      float bv = bias[col];
#pragma unroll
      for (int r = 0; r < 4; r++) {
        int row = m0 + i * 16 + rg * 4 + r;
        C[(long)row * N + col] = acc[i][j][r] + bv;
      }
    }
  }
}

// ---------------------------------------------------------------------------
// GRU elementwise: combines gi, gh -> h_new; writes h_new output and the
// left half of the concat input.
// ---------------------------------------------------------------------------
__global__ __launch_bounds__(256) void gru_ew(
    const float* __restrict__ gi, const float* __restrict__ gh,
    const float* __restrict__ hlast, float* __restrict__ hnew,
    float* __restrict__ cin) {
  int idx = blockIdx.x * 256 + threadIdx.x;  // 0..B*H
  int b = idx >> 9, j = idx & 511;
  const float* gib = gi + b * 1536;
  const float* ghb = gh + b * 1536;
  float gir = gib[j], giz = gib[512 + j], gin = gib[1024 + j];
  float ghr = ghb[j], ghz = ghb[512 + j], ghn = ghb[1024 + j];
  float r = 1.f / (1.f + __expf(-(gir + ghr)));
  float z = 1.f / (1.f + __expf(-(giz + ghz)));
  float n = tanhf(gin + r * ghn);
  float h = (1.f - z) * n + z * hlast[idx];
  hnew[idx] = h;
  cin[b * 1024 + j] = h;
}

// ---------------------------------------------------------------------------
// Fused attention pass 1: per (batch, s-chunk) block, each wave streams 64
// s-rows. Computes e_s = h.enc[b,s,:] from float4 regs, does online softmax
// with in-register context accumulation (enc read from HBM exactly once).
// Writes raw energies + per-wave (m, l, acc[512]) partials.
// ---------------------------------------------------------------------------
__global__ __launch_bounds__(256) void attn_partial(
    const float* __restrict__ enc, const float* __restrict__ hnew,
    float* __restrict__ energies, float* __restrict__ pm,
    float* __restrict__ pl, float* __restrict__ pacc) {
  const int bid = blockIdx.x;
  const int b = bid >> 3;  // / NCH
  const int c = bid & (NCH - 1);
  const int wave = threadIdx.x >> 6;
  const int lane = threadIdx.x & 63;

  const float4* hp = (const float4*)(hnew + b * H_);
  const float4 hA = hp[lane];       // floats [lane*4, lane*4+4)
  const float4 hB = hp[64 + lane];  // floats [256+lane*4, ...)

  float m = -INFINITY, l = 0.f;
  float4 aA = {0.f, 0.f, 0.f, 0.f}, aB = {0.f, 0.f, 0.f, 0.f};
  float my_e = 0.f;
  const int s0 = c * 256 + wave * 64;

#pragma unroll 2
  for (int i = 0; i < 64; ++i) {
    int s = s0 + i;
    const float4* ep = (const float4*)(enc + ((long)b * S_ + s) * H_);
    float4 eA = ep[lane];
    float4 eB = ep[64 + lane];
    float v = eA.x * hA.x + eA.y * hA.y + eA.z * hA.z + eA.w * hA.w +
              eB.x * hB.x + eB.y * hB.y + eB.z * hB.z + eB.w * hB.w;
#pragma unroll
    for (int off = 32; off > 0; off >>= 1) v += __shfl_xor(v, off);
    if (lane == i) my_e = v;  // stash for coalesced energies store
    float mn = fmaxf(m, v);
    float sc = __expf(m - mn);  // first iter: exp(-inf)=0
    float p = __expf(v - mn);
    m = mn;
    l = l * sc + p;
    aA.x = aA.x * sc + p * eA.x;
    aA.y = aA.y * sc + p * eA.y;
    aA.z = aA.z * sc + p * eA.z;
    aA.w = aA.w * sc + p * eA.w;
    aB.x = aB.x * sc + p * eB.x;
    aB.y = aB.y * sc + p * eB.y;
    aB.z = aB.z * sc + p * eB.z;
    aB.w = aB.w * sc + p * eB.w;
  }

  energies[(long)b * S_ + s0 + lane] = my_e;
  int pidx = b * NP + c * NW + wave;
  if (lane == 0) {
    pm[pidx] = m;
    pl[pidx] = l;
  }
  float4* pa = (float4*)(pacc + (long)pidx * H_);
  pa[lane] = aA;
  pa[64 + lane] = aB;
}

// ---------------------------------------------------------------------------
// Attention pass 2: merge 32 partials per batch -> global (m, l); emit
// context into right half of concat input, and normalized attn weights.
// ---------------------------------------------------------------------------
__global__ __launch_bounds__(256) void attn_combine(
    const float* __restrict__ energies, const float* __restrict__ pm,
    const float* __restrict__ pl, const float* __restrict__ pacc,
    float* __restrict__ attn, float* __restrict__ cin) {
  const int b = blockIdx.x;
  const int tid = threadIdx.x;

  float m_b = -INFINITY;
#pragma unroll
  for (int i = 0; i < NP; i++) m_b = fmaxf(m_b, pm[b * NP + i]);
  float wgt[NP];
  float l_b = 0.f;
#pragma unroll
  for (int i = 0; i < NP; i++) {
    wgt[i] = __expf(pm[b * NP + i] - m_b);
    l_b += pl[b * NP + i] * wgt[i];
  }
  float inv = 1.f / l_b;

  for (int k = tid; k < H_; k += 256) {
    float s = 0.f;
#pragma unroll
    for (int i = 0; i < NP; i++)
      s += pacc[(long)(b * NP + i) * H_ + k] * wgt[i];
    cin[b * 1024 + 512 + k] = s * inv;
  }
  for (int s = tid; s < S_; s += 256) {
    attn[(long)b * S_ + s] = __expf(energies[(long)b * S_ + s] - m_b) * inv;
  }
}

// ---------------------------------------------------------------------------
extern "C" void kernel_launch(void* const* d_in, const int* in_sizes, int n_in,
                              void* d_out, int out_size, void* d_ws,
                              size_t ws_size, hipStream_t stream) {
  const int* idx = (const int*)d_in[0];
  const float* hlast = (const float*)d_in[1];   // (B,1,H)
  const float* enc = (const float*)d_in[2];     // (B,S,H)
  const float* emb = (const float*)d_in[3];     // (V,H)
  const float* w_ih = (const float*)d_in[4];    // (3H,H)
  const float* w_hh = (const float*)d_in[5];    // (3H,H)
  const float* b_ih = (const float*)d_in[6];
  const float* b_hh = (const float*)d_in[7];
  const float* W_cat = (const float*)d_in[8];   // (H,2H)
  const float* b_cat = (const float*)d_in[9];
  const float* W_out = (const float*)d_in[10];  // (V,H)
  const float* b_out = (const float*)d_in[11];

  float* out = (float*)d_out;                 // (B,V)
  float* out_h = out + (long)B_ * V_;         // (B,1,H)
  float* out_a = out_h + B_ * H_;             // (B,S,1)

  float* ws = (float*)d_ws;
  float* gi = ws;                              // B*3H
  float* gh = gi + B_ * 3 * H_;                // B*3H
  float* en = gh + B_ * 3 * H_;                // B*S
  float* pm = en + (long)B_ * S_;              // B*NP
  float* pl = pm + B_ * NP;                    // B*NP
  float* pacc = pl + B_ * NP;                  // B*NP*H
  float* cin = pacc + (long)B_ * NP * H_;      // B*2H
  float* cout = cin + B_ * 2 * H_;             // B*H

  dim3 blk(256);
  // GRU gate GEMMs merged into one launch: M=128, N=1536, K=512, z in {gi,gh}
  gru_gates<<<dim3(1536 / 32, 128 / 32, 2), blk, 0, stream>>>(
      emb, idx, hlast, w_ih, w_hh, b_ih, b_hh, gi, gh);
  gru_ew<<<dim3(B_ * H_ / 256), blk, 0, stream>>>(gi, gh, hlast, out_h, cin);
  // Fused single-pass attention
  attn_partial<<<dim3(B_ * NCH), blk, 0, stream>>>(enc, out_h, en, pm, pl,
                                                   pacc);
  attn_combine<<<dim3(B_), blk, 0, stream>>>(en, pm, pl, pacc, out_a, cin);
  // concat GEMM: M=128, N=512, K=1024, tanh; 16x32 tiles -> 128 blocks
  gemm_tn<16, 32, 16, 1, 2, 1><<<dim3(512 / 32, 128 / 16), blk, 0, stream>>>(
      cin, nullptr, W_cat, b_cat, cout, B_, H_, 2 * H_);
  // output GEMM: M=128, N=32000, K=512 -- MFMA bf16 hi/lo split
  gemm_mfma_split<<<dim3(V_ / 128, B_ / 64), blk, 0, stream>>>(
      cout, W_out, b_out, out, B_, V_, H_);
}

// Round 4
// 837.110 us; speedup vs baseline: 1.0702x; 1.0702x over previous
//
// Resubmission of the round-1 kernel (rounds 2-3 hit infra "container failed
// twice"; R0 precedent shows identical kernels pass on retry). This comment
// exists only to perturb the content hash.
#include <hip/hip_runtime.h>
#include <math.h>

#define B_ 128
#define S_ 2048
#define H_ 512
#define V_ 32000
#define NCH 8          // s-chunks per batch for attention
#define NW 4           // waves per block
#define NP (NCH * NW)  // partials per batch = 32

typedef __attribute__((ext_vector_type(8))) short bf16x8;
typedef __attribute__((ext_vector_type(4))) float f32x4;

// fp32 -> bf16 round-to-nearest-even (bit trick), and back.
__device__ __forceinline__ short f2bf(float f) {
  union { float f; unsigned u; } v;
  v.f = f;
  unsigned r = v.u + 0x7fffu + ((v.u >> 16) & 1u);
  return (short)(r >> 16);
}
__device__ __forceinline__ float bf2f(short s) {
  union { unsigned u; float f; } v;
  v.u = ((unsigned)(unsigned short)s) << 16;
  return v.f;
}

// ---------------------------------------------------------------------------
// Tiled fp32 GEMM body: C[M,N] = A[M,K] @ B[N,K]^T + bias[N], opt tanh.
// BK=64-class tiles, float4 global staging along K, transposed LDS store,
// register double-buffer (next tile's loads issued before compute).
// threads = (BM/TM)*(BN/TN) must equal 256; BM*BK and BN*BK multiples of 1024.
// ---------------------------------------------------------------------------
template <int BM, int BN, int BK, int TM, int TN, int ACT>
__device__ __forceinline__ void gemm_body(
    const float* __restrict__ A, const int* __restrict__ arows,
    const float* __restrict__ Bm, const float* __restrict__ bias,
    float* __restrict__ C, int M, int N, int K, int bx, int by) {
  __shared__ __align__(16) float As[BK][BM + 2];
  __shared__ __align__(16) float Bs[BK][BN + 2];
  constexpr int KF4 = BK / 4;
  constexpr int NA = BM * KF4 / 256;  // float4 chunks per thread (A)
  constexpr int NB = BN * KF4 / 256;
  const int tid = threadIdx.x;
  const int tx = tid % (BN / TN);
  const int ty = tid / (BN / TN);
  const int n0 = bx * BN;
  const int m0 = by * BM;

  int aRow[NA];
#pragma unroll
  for (int q = 0; q < NA; q++) {
    int ch = tid + 256 * q;
    int r = ch / KF4;
    aRow[q] = arows ? arows[m0 + r] : (m0 + r);
  }

  float4 ra[NA], rb[NB];
#pragma unroll
  for (int q = 0; q < NA; q++) {
    int ch = tid + 256 * q;
    int c = ch % KF4;
    ra[q] = *(const float4*)(A + (long)aRow[q] * K + 4 * c);
  }
#pragma unroll
  for (int q = 0; q < NB; q++) {
    int ch = tid + 256 * q;
    int r = ch / KF4, c = ch % KF4;
    rb[q] = *(const float4*)(Bm + (long)(n0 + r) * K + 4 * c);
  }

  float acc[TM][TN];
#pragma unroll
  for (int i = 0; i < TM; i++)
#pragma unroll
    for (int j = 0; j < TN; j++) acc[i][j] = 0.f;

  for (int k0 = 0; k0 < K; k0 += BK) {
    // transposed store to LDS
#pragma unroll
    for (int q = 0; q < NA; q++) {
      int ch = tid + 256 * q;
      int r = ch / KF4, c = ch % KF4;
      As[4 * c + 0][r] = ra[q].x;
      As[4 * c + 1][r] = ra[q].y;
      As[4 * c + 2][r] = ra[q].z;
      As[4 * c + 3][r] = ra[q].w;
    }
#pragma unroll
    for (int q = 0; q < NB; q++) {
      int ch = tid + 256 * q;
      int r = ch / KF4, c = ch % KF4;
      Bs[4 * c + 0][r] = rb[q].x;
      Bs[4 * c + 1][r] = rb[q].y;
      Bs[4 * c + 2][r] = rb[q].z;
      Bs[4 * c + 3][r] = rb[q].w;
    }
    __syncthreads();
    if (k0 + BK < K) {  // prefetch next K-tile into regs (hides HBM latency)
#pragma unroll
      for (int q = 0; q < NA; q++) {
        int ch = tid + 256 * q;
        int c = ch % KF4;
        ra[q] = *(const float4*)(A + (long)aRow[q] * K + k0 + BK + 4 * c);
      }
#pragma unroll
      for (int q = 0; q < NB; q++) {
        int ch = tid + 256 * q;
        int r = ch / KF4, c = ch % KF4;
        rb[q] = *(const float4*)(Bm + (long)(n0 + r) * K + k0 + BK + 4 * c);
      }
    }
#pragma unroll
    for (int kk = 0; kk < BK; kk++) {
      float av[TM], bv[TN];
#pragma unroll
      for (int i = 0; i < TM; i++) av[i] = As[kk][ty * TM + i];
#pragma unroll
      for (int j = 0; j < TN; j++) bv[j] = Bs[kk][tx * TN + j];
#pragma unroll
      for (int i = 0; i < TM; i++)
#pragma unroll
        for (int j = 0; j < TN; j++) acc[i][j] = fmaf(av[i], bv[j], acc[i][j]);
    }
    __syncthreads();
  }

#pragma unroll
  for (int i = 0; i < TM; i++) {
    int m = m0 + ty * TM + i;
#pragma unroll
    for (int j = 0; j < TN; j++) {
      int n = n0 + tx * TN + j;
      float c = acc[i][j] + bias[n];
      if (ACT == 1) c = tanhf(c);
      C[(long)m * N + n] = c;
    }
  }
}

template <int BM, int BN, int BK, int TM, int TN, int ACT>
__global__ __launch_bounds__(256) void gemm_tn(
    const float* __restrict__ A, const int* __restrict__ arows,
    const float* __restrict__ Bm, const float* __restrict__ bias,
    float* __restrict__ C, int M, int N, int K) {
  gemm_body<BM, BN, BK, TM, TN, ACT>(A, arows, Bm, bias, C, M, N, K,
                                     blockIdx.x, blockIdx.y);
}

// ---------------------------------------------------------------------------
// Both GRU gate GEMMs in ONE launch (blockIdx.z selects gi vs gh).
// ---------------------------------------------------------------------------
__global__ __launch_bounds__(256) void gru_gates(
    const float* __restrict__ emb, const int* __restrict__ idx,
    const float* __restrict__ hlast, const float* __restrict__ w_ih,
    const float* __restrict__ w_hh, const float* __restrict__ b_ih,
    const float* __restrict__ b_hh, float* __restrict__ gi,
    float* __restrict__ gh) {
  if (blockIdx.z == 0)
    gemm_body<32, 32, 64, 2, 2, 0>(emb, idx, w_ih, b_ih, gi, B_, 3 * H_, H_,
                                   blockIdx.x, blockIdx.y);
  else
    gemm_body<32, 32, 64, 2, 2, 0>(hlast, nullptr, w_hh, b_hh, gh, B_, 3 * H_,
                                   H_, blockIdx.x, blockIdx.y);
}

// ---------------------------------------------------------------------------
// Output GEMM via MFMA, bf16 hi/lo split (3 MFMA passes ~= fp32 accuracy):
//   C[128,N] = A[128,K] @ B[N,K]^T + bias[N], fp32 in/out.
// Tile 128(M) x 128(N), BK=64, grid (N/128, 1): W_out (the HBM-resident
// operand) is fetched exactly once. 4 waves, each owns a 64x64 sub-tile
// (M_rep=4, N_rep=4 of 16x16x32). W_out register-prefetched across the MFMA
// phase. Per-element K-accumulation order identical to R0's kernel
// (k0 asc, ks asc, hh->hl->lh) -> bit-identical numerics.
// ---------------------------------------------------------------------------
__global__ __launch_bounds__(256, 2) void gemm_mfma_split(
    const float* __restrict__ A, const float* __restrict__ Bm,
    const float* __restrict__ bias, float* __restrict__ C, int N, int K) {
  __shared__ __align__(16) short Ah[128][72];
  __shared__ __align__(16) short Al[128][72];
  __shared__ __align__(16) short Bh[128][72];
  __shared__ __align__(16) short Bl[128][72];

  const int tid = threadIdx.x;
  const int wv = tid >> 6;
  const int lane = tid & 63;
  const int n0 = blockIdx.x * 128;
  const int wm = (wv >> 1) * 64;   // wave M offset
  const int wn = (wv & 1) * 64;    // wave N offset

  const int sr = tid >> 1;         // staging row 0..127 (2 thr/row)
  const int sc = (tid & 1) << 5;   // staging col chunk: 32 floats

  const int rr = lane & 15;
  const int kg = (lane >> 4) << 3;  // k-slot base within 32-wide k-step
  const int rg = lane >> 4;

  f32x4 acc[4][4];
#pragma unroll
  for (int i = 0; i < 4; i++)
#pragma unroll
    for (int j = 0; j < 4; j++) acc[i][j] = (f32x4){0.f, 0.f, 0.f, 0.f};

  // prologue: prefetch first W_out tile
  float4 fb[8];
#pragma unroll
  for (int q = 0; q < 8; q++)
    fb[q] = *(const float4*)(Bm + (long)(n0 + sr) * K + sc + 4 * q);

  for (int k0 = 0; k0 < K; k0 += 64) {
    // ---- A tile (L2-hot cout): load + convert + store ----
    {
      float4 fa[8];
#pragma unroll
      for (int q = 0; q < 8; q++)
        fa[q] = *(const float4*)(A + (long)sr * K + k0 + sc + 4 * q);
#pragma unroll
      for (int g = 0; g < 4; g++) {
        float4 u = fa[2 * g], w = fa[2 * g + 1];
        float x[8] = {u.x, u.y, u.z, u.w, w.x, w.y, w.z, w.w};
        bf16x8 hh, ll;
#pragma unroll
        for (int j = 0; j < 8; j++) {
          short h = f2bf(x[j]);
          hh[j] = h;
          ll[j] = f2bf(x[j] - bf2f(h));
        }
        *(bf16x8*)&Ah[sr][sc + 8 * g] = hh;
        *(bf16x8*)&Al[sr][sc + 8 * g] = ll;
      }
    }
    // ---- B tile: convert prefetched regs + store ----
#pragma unroll
    for (int g = 0; g < 4; g++) {
      float4 u = fb[2 * g], w = fb[2 * g + 1];
      float x[8] = {u.x, u.y, u.z, u.w, w.x, w.y, w.z, w.w};
      bf16x8 hh, ll;
#pragma unroll
      for (int j = 0; j < 8; j++) {
        short h = f2bf(x[j]);
        hh[j] = h;
        ll[j] = f2bf(x[j] - bf2f(h));
      }
      *(bf16x8*)&Bh[sr][sc + 8 * g] = hh;
      *(bf16x8*)&Bl[sr][sc + 8 * g] = ll;
    }
    __syncthreads();

    // prefetch next W_out tile; lands during MFMA phase
    if (k0 + 64 < K) {
#pragma unroll
      for (int q = 0; q < 8; q++)
        fb[q] =
            *(const float4*)(Bm + (long)(n0 + sr) * K + k0 + 64 + sc + 4 * q);
    }

#pragma unroll
    for (int ks = 0; ks < 2; ks++) {
      const int kb = ks * 32 + kg;
      bf16x8 a_h[4], a_l[4], b_h[4], b_l[4];
#pragma unroll
      for (int i = 0; i < 4; i++) {
        a_h[i] = *(const bf16x8*)&Ah[wm + i * 16 + rr][kb];
        a_l[i] = *(const bf16x8*)&Al[wm + i * 16 + rr][kb];
      }
#pragma unroll
      for (int j = 0; j < 4; j++) {
        b_h[j] = *(const bf16x8*)&Bh[wn + j * 16 + rr][kb];
        b_l[j] = *(const bf16x8*)&Bl[wn + j * 16 + rr][kb];
      }
#pragma unroll
      for (int i = 0; i < 4; i++)
#pragma unroll
        for (int j = 0; j < 4; j++) {
          acc[i][j] = __builtin_amdgcn_mfma_f32_16x16x32_bf16(
              a_h[i], b_h[j], acc[i][j], 0, 0, 0);
          acc[i][j] = __builtin_amdgcn_mfma_f32_16x16x32_bf16(
              a_h[i], b_l[j], acc[i][j], 0, 0, 0);
          acc[i][j] = __builtin_amdgcn_mfma_f32_16x16x32_bf16(
              a_l[i], b_h[j], acc[i][j], 0, 0, 0);
        }
    }
    __syncthreads();
  }

  // epilogue: C/D layout col=lane&15, row=(lane>>4)*4+reg  [m89-verified]
#pragma unroll
  for (int i = 0; i < 4; i++) {
#pragma unroll
    for (int j = 0; j < 4; j++) {
      int col = n0 + wn + j * 16 + rr;
      float bvv = bias[col];
#pragma unroll
      for (int r = 0; r < 4; r++) {
        int row = wm + i * 16 + rg * 4 + r;
        C[(long)row * N + col] = acc[i][j][r] + bvv;
      }
    }
  }
}

// ---------------------------------------------------------------------------
// GRU elementwise: combines gi, gh -> h_new; writes h_new output and the
// left half of the concat input.
// ---------------------------------------------------------------------------
__global__ __launch_bounds__(256) void gru_ew(
    const float* __restrict__ gi, const float* __restrict__ gh,
    const float* __restrict__ hlast, float* __restrict__ hnew,
    float* __restrict__ cin) {
  int idx = blockIdx.x * 256 + threadIdx.x;  // 0..B*H
  int b = idx >> 9, j = idx & 511;
  const float* gib = gi + b * 1536;
  const float* ghb = gh + b * 1536;
  float gir = gib[j], giz = gib[512 + j], gin = gib[1024 + j];
  float ghr = ghb[j], ghz = ghb[512 + j], ghn = ghb[1024 + j];
  float r = 1.f / (1.f + __expf(-(gir + ghr)));
  float z = 1.f / (1.f + __expf(-(giz + ghz)));
  float n = tanhf(gin + r * ghn);
  float h = (1.f - z) * n + z * hlast[idx];
  hnew[idx] = h;
  cin[b * 1024 + j] = h;
}

// ---------------------------------------------------------------------------
// Fused attention pass 1: per (batch, s-chunk) block, each wave streams 64
// s-rows, 2 rows per iteration (4 float4 loads in flight, paired shfl
// reduces, one combined online-softmax rescale). enc read from HBM once.
// ---------------------------------------------------------------------------
__global__ __launch_bounds__(256) void attn_partial(
    const float* __restrict__ enc, const float* __restrict__ hnew,
    float* __restrict__ energies, float* __restrict__ pm,
    float* __restrict__ pl, float* __restrict__ pacc) {
  const int bid = blockIdx.x;
  const int b = bid >> 3;  // / NCH
  const int c = bid & (NCH - 1);
  const int wave = threadIdx.x >> 6;
  const int lane = threadIdx.x & 63;

  const float4* hp = (const float4*)(hnew + b * H_);
  const float4 hA = hp[lane];       // floats [lane*4, lane*4+4)
  const float4 hB = hp[64 + lane];  // floats [256+lane*4, ...)

  float m = -INFINITY, l = 0.f;
  float4 aA = {0.f, 0.f, 0.f, 0.f}, aB = {0.f, 0.f, 0.f, 0.f};
  float my_e = 0.f;
  const int s0 = c * 256 + wave * 64;

#pragma unroll 2
  for (int i = 0; i < 32; ++i) {
    int s = s0 + 2 * i;
    const float4* ep0 = (const float4*)(enc + ((long)b * S_ + s) * H_);
    const float4* ep1 = (const float4*)(enc + ((long)b * S_ + s + 1) * H_);
    float4 e0A = ep0[lane];
    float4 e0B = ep0[64 + lane];
    float4 e1A = ep1[lane];
    float4 e1B = ep1[64 + lane];
    float v0 = e0A.x * hA.x + e0A.y * hA.y + e0A.z * hA.z + e0A.w * hA.w +
               e0B.x * hB.x + e0B.y * hB.y + e0B.z * hB.z + e0B.w * hB.w;
    float v1 = e1A.x * hA.x + e1A.y * hA.y + e1A.z * hA.z + e1A.w * hA.w +
               e1B.x * hB.x + e1B.y * hB.y + e1B.z * hB.z + e1B.w * hB.w;
#pragma unroll
    for (int off = 32; off > 0; off >>= 1) {
      v0 += __shfl_xor(v0, off);
      v1 += __shfl_xor(v1, off);
    }
    if (lane == 2 * i) my_e = v0;      // stash for coalesced energies store
    if (lane == 2 * i + 1) my_e = v1;
    float mx = fmaxf(v0, v1);
    float mn = fmaxf(m, mx);
    float sc = __expf(m - mn);  // first iter: exp(-inf)=0
    float p0 = __expf(v0 - mn);
    float p1 = __expf(v1 - mn);
    m = mn;
    l = l * sc + p0 + p1;
    aA.x = fmaf(p1, e1A.x, fmaf(p0, e0A.x, aA.x * sc));
    aA.y = fmaf(p1, e1A.y, fmaf(p0, e0A.y, aA.y * sc));
    aA.z = fmaf(p1, e1A.z, fmaf(p0, e0A.z, aA.z * sc));
    aA.w = fmaf(p1, e1A.w, fmaf(p0, e0A.w, aA.w * sc));
    aB.x = fmaf(p1, e1B.x, fmaf(p0, e0B.x, aB.x * sc));
    aB.y = fmaf(p1, e1B.y, fmaf(p0, e0B.y, aB.y * sc));
    aB.z = fmaf(p1, e1B.z, fmaf(p0, e0B.z, aB.z * sc));
    aB.w = fmaf(p1, e1B.w, fmaf(p0, e0B.w, aB.w * sc));
  }

  energies[(long)b * S_ + s0 + lane] = my_e;
  int pidx = b * NP + c * NW + wave;
  if (lane == 0) {
    pm[pidx] = m;
    pl[pidx] = l;
  }
  float4* pa = (float4*)(pacc + (long)pidx * H_);
  pa[lane] = aA;
  pa[64 + lane] = aB;
}

// ---------------------------------------------------------------------------
// Attention pass 2: merge 32 partials per batch -> global (m, l); emit
// context into right half of concat input, and normalized attn weights.
// ---------------------------------------------------------------------------
__global__ __launch_bounds__(256) void attn_combine(
    const float* __restrict__ energies, const float* __restrict__ pm,
    const float* __restrict__ pl, const float* __restrict__ pacc,
    float* __restrict__ attn, float* __restrict__ cin) {
  const int b = blockIdx.x;
  const int tid = threadIdx.x;

  float m_b = -INFINITY;
#pragma unroll
  for (int i = 0; i < NP; i++) m_b = fmaxf(m_b, pm[b * NP + i]);
  float wgt[NP];
  float l_b = 0.f;
#pragma unroll
  for (int i = 0; i < NP; i++) {
    wgt[i] = __expf(pm[b * NP + i] - m_b);
    l_b += pl[b * NP + i] * wgt[i];
  }
  float inv = 1.f / l_b;

  for (int k = tid; k < H_; k += 256) {
    float s = 0.f;
#pragma unroll
    for (int i = 0; i < NP; i++)
      s += pacc[(long)(b * NP + i) * H_ + k] * wgt[i];
    cin[b * 1024 + 512 + k] = s * inv;
  }
  for (int s = tid; s < S_; s += 256) {
    attn[(long)b * S_ + s] = __expf(energies[(long)b * S_ + s] - m_b) * inv;
  }
}

// ---------------------------------------------------------------------------
extern "C" void kernel_launch(void* const* d_in, const int* in_sizes, int n_in,
                              void* d_out, int out_size, void* d_ws,
                              size_t ws_size, hipStream_t stream) {
  const int* idx = (const int*)d_in[0];
  const float* hlast = (const float*)d_in[1];   // (B,1,H)
  const float* enc = (const float*)d_in[2];     // (B,S,H)
  const float* emb = (const float*)d_in[3];     // (V,H)
  const float* w_ih = (const float*)d_in[4];    // (3H,H)
  const float* w_hh = (const float*)d_in[5];    // (3H,H)
  const float* b_ih = (const float*)d_in[6];
  const float* b_hh = (const float*)d_in[7];
  const float* W_cat = (const float*)d_in[8];   // (H,2H)
  const float* b_cat = (const float*)d_in[9];
  const float* W_out = (const float*)d_in[10];  // (V,H)
  const float* b_out = (const float*)d_in[11];

  float* out = (float*)d_out;                 // (B,V)
  float* out_h = out + (long)B_ * V_;         // (B,1,H)
  float* out_a = out_h + B_ * H_;             // (B,S,1)

  float* ws = (float*)d_ws;
  float* gi = ws;                              // B*3H
  float* gh = gi + B_ * 3 * H_;                // B*3H
  float* en = gh + B_ * 3 * H_;                // B*S
  float* pm = en + (long)B_ * S_;              // B*NP
  float* pl = pm + B_ * NP;                    // B*NP
  float* pacc = pl + B_ * NP;                  // B*NP*H
  float* cin = pacc + (long)B_ * NP * H_;      // B*2H
  float* cout = cin + B_ * 2 * H_;             // B*H

  dim3 blk(256);
  // GRU gate GEMMs merged into one launch: M=128, N=1536, K=512, z in {gi,gh}
  gru_gates<<<dim3(1536 / 32, 128 / 32, 2), blk, 0, stream>>>(
      emb, idx, hlast, w_ih, w_hh, b_ih, b_hh, gi, gh);
  gru_ew<<<dim3(B_ * H_ / 256), blk, 0, stream>>>(gi, gh, hlast, out_h, cin);
  // Fused single-pass attention
  attn_partial<<<dim3(B_ * NCH), blk, 0, stream>>>(enc, out_h, en, pm, pl,
                                                   pacc);
  attn_combine<<<dim3(B_), blk, 0, stream>>>(en, pm, pl, pacc, out_a, cin);
  // concat GEMM: M=128, N=512, K=1024, tanh; 16x32 tiles -> 128 blocks
  gemm_tn<16, 32, 64, 1, 2, 1><<<dim3(512 / 32, 128 / 16), blk, 0, stream>>>(
      cin, nullptr, W_cat, b_cat, cout, B_, H_, 2 * H_);
  // output GEMM: M=128, N=32000, K=512 -- MFMA bf16 hi/lo split, W_out
  // fetched exactly once (BM=128 covers all of M)
  gemm_mfma_split<<<dim3(V_ / 128), blk, 0, stream>>>(cout, W_out, b_out, out,
                                                      V_, H_);
}